// Round 4
// baseline (659.419 us; speedup 1.0000x reference)
//
#include <hip/hip_runtime.h>

#define T_TOK 8192
#define DIM   1024
#define DFF   4096
#define NEXP  8
#define NREG  5

typedef __attribute__((ext_vector_type(8))) __bf16 bf16x8;
typedef __attribute__((ext_vector_type(4))) float f32x4;
typedef __attribute__((ext_vector_type(4))) unsigned short us4;

__device__ inline unsigned short f2bf(float f) {
  unsigned int u = __builtin_bit_cast(unsigned int, f);
  u += 0x7fffu + ((u >> 16) & 1u);          // RNE
  return (unsigned short)(u >> 16);
}

__device__ inline void gll16(const void* g, void* l) {
  __builtin_amdgcn_global_load_lds(
      (__attribute__((address_space(1))) void*)(g),
      (__attribute__((address_space(3))) void*)(l), 16, 0, 0);
}

__device__ inline float gelu_tanh(float x) {
  float y = 0.7978845608028654f * (x + 0.044715f * x * x * x);
  float e = __expf(2.f * y);
  float t = 1.f - 2.f / (e + 1.f);
  return 0.5f * x * (1.f + t);
}

// ---------------- K1: weights fp32 -> bf16 (+ zero counts) ----------------
__global__ __launch_bounds__(256) void convert_w_kernel(
    const float* __restrict__ w1, const float* __restrict__ w2,
    unsigned short* __restrict__ w1b, unsigned short* __restrict__ w2b,
    int* __restrict__ counts) {
  if (blockIdx.x == 0 && threadIdx.x < 16) counts[threadIdx.x] = 0;
  const long N4 = (long)NREG * DFF * DIM / 4;   // float4 count per tensor
  long stride = (long)gridDim.x * 256;
  for (long p = (long)blockIdx.x * 256 + threadIdx.x; p < 2 * N4; p += stride) {
    const float* src = (p < N4) ? &w1[p * 4] : &w2[(p - N4) * 4];
    unsigned short* dst = (p < N4) ? &w1b[p * 4] : &w2b[(p - N4) * 4];
    float4 v = *(const float4*)src;
    us4 b = {f2bf(v.x), f2bf(v.y), f2bf(v.z), f2bf(v.w)};
    *(us4*)dst = b;
  }
}

// ---------------- K2: router layer 1: htmp = tanh(x @ wg1^T) ----------------
__global__ __launch_bounds__(256) void router1_kernel(
    const float* __restrict__ x, const float* __restrict__ wg1,
    float* __restrict__ htmp) {
  __shared__ float xs[64][68];
  __shared__ float ws[64][68];
  const int t0 = blockIdx.x * 64;
  const int tid = threadIdx.x;
  const int tr = tid >> 4, tc = tid & 15;
  float acc[4][4] = {};
  for (int k0 = 0; k0 < DIM; k0 += 64) {
    #pragma unroll
    for (int i = 0; i < 4; i++) {
      int idx = tid + i * 256;
      int r = idx >> 4, c4 = idx & 15;
      *(float4*)&xs[r][c4 * 4] = *(const float4*)&x[(long)(t0 + r) * DIM + k0 + c4 * 4];
      *(float4*)&ws[r][c4 * 4] = *(const float4*)&wg1[(long)r * DIM + k0 + c4 * 4];
    }
    __syncthreads();
    #pragma unroll
    for (int kk = 0; kk < 64; kk += 4) {
      float4 a[4], b[4];
      #pragma unroll
      for (int i = 0; i < 4; i++) a[i] = *(const float4*)&xs[tr * 4 + i][kk];
      #pragma unroll
      for (int j = 0; j < 4; j++) b[j] = *(const float4*)&ws[tc * 4 + j][kk];
      #pragma unroll
      for (int i = 0; i < 4; i++)
        #pragma unroll
        for (int j = 0; j < 4; j++)
          acc[i][j] += a[i].x * b[j].x + a[i].y * b[j].y + a[i].z * b[j].z + a[i].w * b[j].w;
    }
    __syncthreads();
  }
  #pragma unroll
  for (int i = 0; i < 4; i++)
    #pragma unroll
    for (int j = 0; j < 4; j++)
      htmp[(long)(t0 + tr * 4 + i) * 64 + tc * 4 + j] = tanhf(acc[i][j]);
}

// ---------------- K3: router layer 2 + gating + compaction ----------------
__global__ __launch_bounds__(256) void gate_kernel(
    const float* __restrict__ htmp, const float* __restrict__ wg2,
    float* __restrict__ logits_out, float* __restrict__ wcc,
    int* __restrict__ counts, int* __restrict__ tok_list,
    float* __restrict__ wt_list) {
  __shared__ float w2s[NEXP * 64];
  const int tid = threadIdx.x;
  for (int i = tid; i < NEXP * 64; i += 256) w2s[i] = wg2[i];
  __syncthreads();
  const int t = blockIdx.x * 256 + tid;

  float h[64];
  #pragma unroll
  for (int i = 0; i < 64; i += 4)
    *(float4*)&h[i] = *(const float4*)&htmp[(long)t * 64 + i];

  float lg[NEXP];
  #pragma unroll
  for (int e = 0; e < NEXP; e++) {
    float s = 0.f;
    #pragma unroll
    for (int j = 0; j < 64; j++) s += h[j] * w2s[e * 64 + j];
    lg[e] = s;
  }
  #pragma unroll
  for (int e = 0; e < NEXP; e++) logits_out[(long)t * NEXP + e] = lg[e];

  float m = lg[0];
  #pragma unroll
  for (int e = 1; e < NEXP; e++) m = fmaxf(m, lg[e]);
  float ex[NEXP], sum = 0.f;
  #pragma unroll
  for (int e = 0; e < NEXP; e++) { ex[e] = expf(lg[e] - m); sum += ex[e]; }

  int i1 = 0; float v1 = ex[0];
  #pragma unroll
  for (int e = 1; e < NEXP; e++) if (ex[e] > v1) { v1 = ex[e]; i1 = e; }
  int i2 = -1; float v2 = -1.f;
  #pragma unroll
  for (int e = 0; e < NEXP; e++) if (e != i1 && ex[e] > v2) { v2 = ex[e]; i2 = e; }
  v1 /= sum; v2 /= sum;
  float z1 = (i1 == NEXP - 1) ? 0.f : v1;
  float z2 = (i2 == NEXP - 1) ? 0.f : v2;
  float s2 = z1 + z2;
  float w1v = z1 / s2, w2v = z2 / s2;

  int   sel_i[2] = {i1, i2};
  float sel_w[2] = {w1v, w2v};
  float wc = 0.f, wcp = 0.f;
  #pragma unroll
  for (int s = 0; s < 2; s++) {
    int e = sel_i[s]; float w = sel_w[s];
    if (e < NREG) {
      int pos = atomicAdd(&counts[e], 1);
      tok_list[e * T_TOK + pos] = t;
      wt_list[e * T_TOK + pos] = w;
    } else if (e == NREG) wc = w;
    else if (e == NREG + 1) wcp = w;
  }
  wcc[t * 2 + 0] = wc;
  wcc[t * 2 + 1] = wcp;
}

// ---------------- K4: x2 = 2x -> bf16, out init with Const+Copy experts ----------------
__global__ __launch_bounds__(256) void x2init_kernel(
    const float* __restrict__ x, const float* __restrict__ const_c,
    const float* __restrict__ const_wg, const float* __restrict__ wcc,
    unsigned short* __restrict__ x2b, float* __restrict__ out) {
  const int t = blockIdx.x;
  const int tid = threadIdx.x;
  const int c0 = tid * 4;
  float4 v = *(const float4*)&x[(long)t * DIM + c0];
  float4 x2 = make_float4(2.f * v.x, 2.f * v.y, 2.f * v.z, 2.f * v.w);
  us4 xb = {f2bf(x2.x), f2bf(x2.y), f2bf(x2.z), f2bf(x2.w)};
  *(us4*)&x2b[(long)t * DIM + c0] = xb;

  float4 g0 = *(const float4*)&const_wg[c0];
  float4 g1 = *(const float4*)&const_wg[DIM + c0];
  float d0 = x2.x * g0.x + x2.y * g0.y + x2.z * g0.z + x2.w * g0.w;
  float d1 = x2.x * g1.x + x2.y * g1.y + x2.z * g1.z + x2.w * g1.w;
  #pragma unroll
  for (int off = 32; off; off >>= 1) {
    d0 += __shfl_down(d0, off);
    d1 += __shfl_down(d1, off);
  }
  __shared__ float red[8];
  const int lane = tid & 63, wid = tid >> 6;
  if (lane == 0) { red[wid] = d0; red[4 + wid] = d1; }
  __syncthreads();
  d0 = red[0] + red[1] + red[2] + red[3];
  d1 = red[4] + red[5] + red[6] + red[7];
  float mm = fmaxf(d0, d1);
  float e0 = expf(d0 - mm), e1 = expf(d1 - mm);
  float cw0 = e0 / (e0 + e1), cw1 = e1 / (e0 + e1);
  float wc = wcc[t * 2 + 0], wcp = wcc[t * 2 + 1];
  float4 cc = *(const float4*)&const_c[c0];
  float4 o;
  o.x = wc * (cw0 * x2.x + cw1 * cc.x) + wcp * x2.x;
  o.y = wc * (cw0 * x2.y + cw1 * cc.y) + wcp * x2.y;
  o.z = wc * (cw0 * x2.z + cw1 * cc.z) + wcp * x2.z;
  o.w = wc * (cw0 * x2.w + cw1 * cc.w) + wcp * x2.w;
  *(float4*)&out[(long)t * DIM + c0] = o;
}

// ---------------- K5/K6: bf16 MFMA GEMM, 256x256 tile, 8 waves, BK=64 ----------------
// Compute phase/K-step = 64 MFMA/wave x 2 waves/SIMD ~= 620 cy ~= load latency,
// so the 1-deep counted-vmcnt(8) prefetch actually covers the L2/L3 miss latency.
// MODE 0: C = gelu(Xg @ W1^T) -> H (bf16). A rows gathered via tok_list.
// MODE 1: out[token] += w * (H @ W2^T), split-K via z = expert*KSPLIT + ks.
template <int KTOT, int NB, int MODE, int KSPLIT>
__global__ __launch_bounds__(512, 2) void gemm_kernel(
    const unsigned short* __restrict__ Ag, const unsigned short* __restrict__ Bg,
    unsigned short* __restrict__ H, float* __restrict__ out,
    const int* __restrict__ counts, const int* __restrict__ tok_list,
    const float* __restrict__ wt_list) {
  const int z = blockIdx.z;
  const int expert = MODE ? (z / KSPLIT) : z;
  const int kbase = MODE ? (z % KSPLIT) * (KTOT / KSPLIT) : 0;
  const int Ne = counts[expert];
  if ((int)blockIdx.y * 256 >= Ne) return;
  int offz = 0;
  for (int e = 0; e < expert; e++) offz += counts[e];

  const int tid = threadIdx.x;        // 0..511
  const int lane = tid & 63;
  const int wid = tid >> 6;           // 0..7
  const int wm = wid >> 2, wn = wid & 3;   // 2 x 4 wave grid

  __shared__ unsigned short As[2][256 * 64];
  __shared__ unsigned short Bs[2][256 * 64];

  const int srow = tid >> 3;     // 0..63 within each 64-row issue
  const int schunk = tid & 7;    // 16B chunk within 128B row

  const unsigned short* aptr[4];
  const unsigned short* bptr[4];
  #pragma unroll
  for (int i = 0; i < 4; i++) {
    int rr = i * 64 + srow;
    int m = blockIdx.y * 256 + rr;
    int mm = (m < Ne) ? m : (Ne - 1);
    long arow;
    if (MODE == 0) arow = (long)tok_list[expert * T_TOK + mm] * KTOT;
    else           arow = (long)(offz + mm) * KTOT;
    // pre-swizzled global source (rule #21): LDS dest stays linear
    aptr[i] = Ag + arow + kbase + ((schunk ^ (rr & 7)) * 8);
    int nr = blockIdx.x * 256 + rr;
    bptr[i] = Bg + (long)expert * NB * KTOT + (long)nr * KTOT + kbase + ((schunk ^ (rr & 7)) * 8);
  }

  f32x4 acc[8][4];
  #pragma unroll
  for (int i = 0; i < 8; i++)
    #pragma unroll
    for (int j = 0; j < 4; j++) acc[i][j] = (f32x4){0.f, 0.f, 0.f, 0.f};

  auto STAGE = [&](int buf, int t) {
    unsigned short* ad = &As[buf][wid * 512];
    unsigned short* bd = &Bs[buf][wid * 512];
    const int k0 = t * 64;
    #pragma unroll
    for (int i = 0; i < 4; i++) {
      gll16(aptr[i] + k0, ad + i * 4096);
      gll16(bptr[i] + k0, bd + i * 4096);
    }
  };

  const int NT = (KTOT / KSPLIT) / 64;
  STAGE(0, 0);
  for (int t = 0; t < NT; ++t) {
    if (t + 1 < NT) {
      STAGE((t + 1) & 1, t + 1);
      asm volatile("s_waitcnt vmcnt(8)" ::: "memory");   // tile t done; t+1 in flight
    } else {
      asm volatile("s_waitcnt vmcnt(0)" ::: "memory");
    }
    __builtin_amdgcn_s_barrier();
    __builtin_amdgcn_sched_barrier(0);
    const unsigned short* as = &As[t & 1][0];
    const unsigned short* bs = &Bs[t & 1][0];
    #pragma unroll
    for (int kk = 0; kk < 2; kk++) {
      bf16x8 av[8], bv[4];
      #pragma unroll
      for (int i = 0; i < 8; i++) {
        int row = wm * 128 + i * 16 + (lane & 15);
        int ch = ((lane >> 4) + kk * 4) ^ (row & 7);
        av[i] = *(const bf16x8*)&as[row * 64 + ch * 8];
      }
      #pragma unroll
      for (int j = 0; j < 4; j++) {
        int row = wn * 64 + j * 16 + (lane & 15);
        int ch = ((lane >> 4) + kk * 4) ^ (row & 7);
        bv[j] = *(const bf16x8*)&bs[row * 64 + ch * 8];
      }
      #pragma unroll
      for (int i = 0; i < 8; i++)
        #pragma unroll
        for (int j = 0; j < 4; j++)
          acc[i][j] = __builtin_amdgcn_mfma_f32_16x16x32_bf16(av[i], bv[j], acc[i][j], 0, 0, 0);
    }
    __builtin_amdgcn_sched_barrier(0);   // pin: all LDS reads complete above
    __builtin_amdgcn_s_barrier();        // safe to overwrite buf[t&1] next iter
    __builtin_amdgcn_sched_barrier(0);
  }

  const int mbase = blockIdx.y * 256 + wm * 128 + (lane >> 4) * 4;
  const int nbase = blockIdx.x * 256 + wn * 64 + (lane & 15);
  #pragma unroll
  for (int i = 0; i < 8; i++) {
    #pragma unroll
    for (int j = 0; j < 4; j++) {
      #pragma unroll
      for (int rr = 0; rr < 4; rr++) {
        int m = mbase + i * 16 + rr;
        int n = nbase + j * 16;
        if (m < Ne) {
          float v = acc[i][j][rr];
          if (MODE == 0) {
            H[(long)(offz + m) * DFF + n] = f2bf(gelu_tanh(v));
          } else {
            float w = wt_list[expert * T_TOK + m];
            int token = tok_list[expert * T_TOK + m];
            atomicAdd(&out[(long)token * DIM + n], w * v);
          }
        }
      }
    }
  }
}

// ---------------- host ----------------
extern "C" void kernel_launch(void* const* d_in, const int* in_sizes, int n_in,
                              void* d_out, int out_size, void* d_ws, size_t ws_size,
                              hipStream_t stream) {
  const float* x    = (const float*)d_in[0];
  const float* wg1  = (const float*)d_in[1];
  const float* wg2  = (const float*)d_in[2];
  const float* ew1  = (const float*)d_in[3];
  const float* ew2  = (const float*)d_in[4];
  const float* cc   = (const float*)d_in[5];
  const float* cwg  = (const float*)d_in[6];

  float* out    = (float*)d_out;                      // [T,1024]
  float* logits = out + (size_t)T_TOK * DIM;          // [T,8]

  char* ws = (char*)d_ws;
  const size_t O_W1B  = 0;
  const size_t O_W2B  = O_W1B + (size_t)NREG * DFF * DIM * 2;
  const size_t O_X2B  = O_W2B + (size_t)NREG * DFF * DIM * 2;
  const size_t O_HTMP = O_X2B + (size_t)T_TOK * DIM * 2;
  const size_t O_CNT  = O_HTMP + (size_t)T_TOK * 64 * 4;
  const size_t O_WCC  = O_CNT + 256;
  const size_t O_TOK  = O_WCC + (size_t)T_TOK * 2 * 4;
  const size_t O_WT   = O_TOK + (size_t)NREG * T_TOK * 4;
  const size_t O_H    = O_WT + (size_t)NREG * T_TOK * 4;

  unsigned short* w1b  = (unsigned short*)(ws + O_W1B);
  unsigned short* w2b  = (unsigned short*)(ws + O_W2B);
  unsigned short* x2b  = (unsigned short*)(ws + O_X2B);
  float*          htmp = (float*)(ws + O_HTMP);
  int*            cnt  = (int*)(ws + O_CNT);
  float*          wcc  = (float*)(ws + O_WCC);
  int*            tok  = (int*)(ws + O_TOK);
  float*          wt   = (float*)(ws + O_WT);
  unsigned short* Hb   = (unsigned short*)(ws + O_H);

  convert_w_kernel<<<2048, 256, 0, stream>>>(ew1, ew2, w1b, w2b, cnt);
  router1_kernel<<<T_TOK / 64, 256, 0, stream>>>(x, wg1, htmp);
  gate_kernel<<<T_TOK / 256, 256, 0, stream>>>(htmp, wg2, logits, wcc, cnt, tok, wt);
  x2init_kernel<<<T_TOK, 256, 0, stream>>>(x, cc, cwg, wcc, x2b, out);
  gemm_kernel<DIM, DFF, 0, 1><<<dim3(DFF / 256, T_TOK / 256, NREG), 512, 0, stream>>>(
      x2b, w1b, Hb, nullptr, cnt, tok, wt);
  gemm_kernel<DFF, DIM, 1, 4><<<dim3(DIM / 256, T_TOK / 256, NREG * 4), 512, 0, stream>>>(
      Hb, w2b, nullptr, out, cnt, tok, wt);
}

// Round 5
// 524.024 us; speedup vs baseline: 1.2584x; 1.2584x over previous
//
#include <hip/hip_runtime.h>

#define T_TOK 8192
#define DIM   1024
#define DFF   4096
#define NEXP  8
#define NREG  5

typedef __attribute__((ext_vector_type(8))) __bf16 bf16x8;
typedef __attribute__((ext_vector_type(4))) float f32x4;
typedef __attribute__((ext_vector_type(4))) unsigned short us4;

__device__ inline unsigned short f2bf(float f) {
  unsigned int u = __builtin_bit_cast(unsigned int, f);
  u += 0x7fffu + ((u >> 16) & 1u);          // RNE
  return (unsigned short)(u >> 16);
}

__device__ inline void gll16(const void* g, void* l) {
  __builtin_amdgcn_global_load_lds(
      (__attribute__((address_space(1))) void*)(g),
      (__attribute__((address_space(3))) void*)(l), 16, 0, 0);
}

__device__ inline float gelu_tanh(float x) {
  float y = 0.7978845608028654f * (x + 0.044715f * x * x * x);
  float e = __expf(2.f * y);
  float t = 1.f - 2.f / (e + 1.f);
  return 0.5f * x * (1.f + t);
}

// ---------------- K1: weights fp32 -> bf16 (+ zero counts) ----------------
__global__ __launch_bounds__(256) void convert_w_kernel(
    const float* __restrict__ w1, const float* __restrict__ w2,
    unsigned short* __restrict__ w1b, unsigned short* __restrict__ w2b,
    int* __restrict__ counts) {
  if (blockIdx.x == 0 && threadIdx.x < 16) counts[threadIdx.x] = 0;
  const long N4 = (long)NREG * DFF * DIM / 4;   // float4 count per tensor
  long stride = (long)gridDim.x * 256;
  for (long p = (long)blockIdx.x * 256 + threadIdx.x; p < 2 * N4; p += stride) {
    const float* src = (p < N4) ? &w1[p * 4] : &w2[(p - N4) * 4];
    unsigned short* dst = (p < N4) ? &w1b[p * 4] : &w2b[(p - N4) * 4];
    float4 v = *(const float4*)src;
    us4 b = {f2bf(v.x), f2bf(v.y), f2bf(v.z), f2bf(v.w)};
    *(us4*)dst = b;
  }
}

// ---------------- K2: router layer 1: htmp = tanh(x @ wg1^T) ----------------
__global__ __launch_bounds__(256) void router1_kernel(
    const float* __restrict__ x, const float* __restrict__ wg1,
    float* __restrict__ htmp) {
  __shared__ float xs[64][68];
  __shared__ float ws[64][68];
  const int t0 = blockIdx.x * 64;
  const int tid = threadIdx.x;
  const int tr = tid >> 4, tc = tid & 15;
  float acc[4][4] = {};
  for (int k0 = 0; k0 < DIM; k0 += 64) {
    #pragma unroll
    for (int i = 0; i < 4; i++) {
      int idx = tid + i * 256;
      int r = idx >> 4, c4 = idx & 15;
      *(float4*)&xs[r][c4 * 4] = *(const float4*)&x[(long)(t0 + r) * DIM + k0 + c4 * 4];
      *(float4*)&ws[r][c4 * 4] = *(const float4*)&wg1[(long)r * DIM + k0 + c4 * 4];
    }
    __syncthreads();
    #pragma unroll
    for (int kk = 0; kk < 64; kk += 4) {
      float4 a[4], b[4];
      #pragma unroll
      for (int i = 0; i < 4; i++) a[i] = *(const float4*)&xs[tr * 4 + i][kk];
      #pragma unroll
      for (int j = 0; j < 4; j++) b[j] = *(const float4*)&ws[tc * 4 + j][kk];
      #pragma unroll
      for (int i = 0; i < 4; i++)
        #pragma unroll
        for (int j = 0; j < 4; j++)
          acc[i][j] += a[i].x * b[j].x + a[i].y * b[j].y + a[i].z * b[j].z + a[i].w * b[j].w;
    }
    __syncthreads();
  }
  #pragma unroll
  for (int i = 0; i < 4; i++)
    #pragma unroll
    for (int j = 0; j < 4; j++)
      htmp[(long)(t0 + tr * 4 + i) * 64 + tc * 4 + j] = tanhf(acc[i][j]);
}

// ---------------- K3: router layer 2 + gating + compaction ----------------
__global__ __launch_bounds__(256) void gate_kernel(
    const float* __restrict__ htmp, const float* __restrict__ wg2,
    float* __restrict__ logits_out, float* __restrict__ wcc,
    int* __restrict__ counts, int* __restrict__ tok_list,
    float* __restrict__ wt_list) {
  __shared__ float w2s[NEXP * 64];
  const int tid = threadIdx.x;
  for (int i = tid; i < NEXP * 64; i += 256) w2s[i] = wg2[i];
  __syncthreads();
  const int t = blockIdx.x * 256 + tid;

  float h[64];
  #pragma unroll
  for (int i = 0; i < 64; i += 4)
    *(float4*)&h[i] = *(const float4*)&htmp[(long)t * 64 + i];

  float lg[NEXP];
  #pragma unroll
  for (int e = 0; e < NEXP; e++) {
    float s = 0.f;
    #pragma unroll
    for (int j = 0; j < 64; j++) s += h[j] * w2s[e * 64 + j];
    lg[e] = s;
  }
  #pragma unroll
  for (int e = 0; e < NEXP; e++) logits_out[(long)t * NEXP + e] = lg[e];

  float m = lg[0];
  #pragma unroll
  for (int e = 1; e < NEXP; e++) m = fmaxf(m, lg[e]);
  float ex[NEXP], sum = 0.f;
  #pragma unroll
  for (int e = 0; e < NEXP; e++) { ex[e] = expf(lg[e] - m); sum += ex[e]; }

  int i1 = 0; float v1 = ex[0];
  #pragma unroll
  for (int e = 1; e < NEXP; e++) if (ex[e] > v1) { v1 = ex[e]; i1 = e; }
  int i2 = -1; float v2 = -1.f;
  #pragma unroll
  for (int e = 0; e < NEXP; e++) if (e != i1 && ex[e] > v2) { v2 = ex[e]; i2 = e; }
  v1 /= sum; v2 /= sum;
  float z1 = (i1 == NEXP - 1) ? 0.f : v1;
  float z2 = (i2 == NEXP - 1) ? 0.f : v2;
  float s2 = z1 + z2;
  float w1v = z1 / s2, w2v = z2 / s2;

  int   sel_i[2] = {i1, i2};
  float sel_w[2] = {w1v, w2v};
  float wc = 0.f, wcp = 0.f;
  #pragma unroll
  for (int s = 0; s < 2; s++) {
    int e = sel_i[s]; float w = sel_w[s];
    if (e < NREG) {
      int pos = atomicAdd(&counts[e], 1);
      tok_list[e * T_TOK + pos] = t;
      wt_list[e * T_TOK + pos] = w;
    } else if (e == NREG) wc = w;
    else if (e == NREG + 1) wcp = w;
  }
  wcc[t * 2 + 0] = wc;
  wcc[t * 2 + 1] = wcp;
}

// ---------------- K4: x2 = 2x -> bf16, out init with Const+Copy experts ----------------
__global__ __launch_bounds__(256) void x2init_kernel(
    const float* __restrict__ x, const float* __restrict__ const_c,
    const float* __restrict__ const_wg, const float* __restrict__ wcc,
    unsigned short* __restrict__ x2b, float* __restrict__ out) {
  const int t = blockIdx.x;
  const int tid = threadIdx.x;
  const int c0 = tid * 4;
  float4 v = *(const float4*)&x[(long)t * DIM + c0];
  float4 x2 = make_float4(2.f * v.x, 2.f * v.y, 2.f * v.z, 2.f * v.w);
  us4 xb = {f2bf(x2.x), f2bf(x2.y), f2bf(x2.z), f2bf(x2.w)};
  *(us4*)&x2b[(long)t * DIM + c0] = xb;

  float4 g0 = *(const float4*)&const_wg[c0];
  float4 g1 = *(const float4*)&const_wg[DIM + c0];
  float d0 = x2.x * g0.x + x2.y * g0.y + x2.z * g0.z + x2.w * g0.w;
  float d1 = x2.x * g1.x + x2.y * g1.y + x2.z * g1.z + x2.w * g1.w;
  #pragma unroll
  for (int off = 32; off; off >>= 1) {
    d0 += __shfl_down(d0, off);
    d1 += __shfl_down(d1, off);
  }
  __shared__ float red[8];
  const int lane = tid & 63, wid = tid >> 6;
  if (lane == 0) { red[wid] = d0; red[4 + wid] = d1; }
  __syncthreads();
  d0 = red[0] + red[1] + red[2] + red[3];
  d1 = red[4] + red[5] + red[6] + red[7];
  float mm = fmaxf(d0, d1);
  float e0 = expf(d0 - mm), e1 = expf(d1 - mm);
  float cw0 = e0 / (e0 + e1), cw1 = e1 / (e0 + e1);
  float wc = wcc[t * 2 + 0], wcp = wcc[t * 2 + 1];
  float4 cc = *(const float4*)&const_c[c0];
  float4 o;
  o.x = wc * (cw0 * x2.x + cw1 * cc.x) + wcp * x2.x;
  o.y = wc * (cw0 * x2.y + cw1 * cc.y) + wcp * x2.y;
  o.z = wc * (cw0 * x2.z + cw1 * cc.z) + wcp * x2.z;
  o.w = wc * (cw0 * x2.w + cw1 * cc.w) + wcp * x2.w;
  *(float4*)&out[(long)t * DIM + c0] = o;
}

// ---------------- K5/K6: bf16 MFMA GEMM, 128x128 tile, BK=64, 4 waves ----------------
// 2-D XCD-rectangle remap: per expert-z the (NX x nact) block grid is tiled into
// 8 contiguous rectangles, one per XCD (xcd = linear_id & 7; per-z grid size is a
// multiple of 8). Per-XCD L2 working set = rect_N*256KB (B) + rect_M*256KB (A)
// ~= 4 MB = one XCD L2, so staging reads become L2 hits instead of L3/HBM misses.
// MODE 0: C = gelu(Xg @ W1^T) -> H (bf16). A rows gathered via tok_list.
// MODE 1: out[token] += w * (H @ W2^T), split-K via z = expert*KSPLIT + ks.
template <int KTOT, int NB, int MODE, int KSPLIT>
__global__ __launch_bounds__(256) void gemm_kernel(
    const unsigned short* __restrict__ Ag, const unsigned short* __restrict__ Bg,
    unsigned short* __restrict__ H, float* __restrict__ out,
    const int* __restrict__ counts, const int* __restrict__ tok_list,
    const float* __restrict__ wt_list) {
  const int z = blockIdx.z;
  const int expert = MODE ? (z / KSPLIT) : z;
  const int kbase = MODE ? (z % KSPLIT) * (KTOT / KSPLIT) : 0;
  const int Ne = counts[expert];
  const int nact = (Ne + 127) >> 7;
  constexpr int NXB = NB / 128;               // N-panels in grid x
  const int p = blockIdx.y * NXB + blockIdx.x;
  if (p >= NXB * nact) return;

  // 2-D XCD rectangles: XC cols x XR rows of XCD-tiles over the (NXB x nact) grid
  constexpr int XC = (MODE == 0) ? 4 : 2;     // G1: 4x2 of 8Nx(nact/2); G2: 2x4 of 4Nx(nact/4)
  constexpr int XR = 8 / XC;
  constexpr int CW = NXB / XC;                // rect width in N-panels
  int i_n, i_m;
  if ((nact % XR) == 0) {
    const int xcd = p & 7, i = p >> 3;        // i in [0, NXB*nact/8)
    i_n = (xcd % XC) * CW + (i % CW);
    i_m = (xcd / XC) * (nact / XR) + (i / CW);
  } else {                                    // fallback: natural order
    i_n = p % NXB;
    i_m = p / NXB;
  }
  if (i_m * 128 >= Ne) return;

  int offz = 0;
  for (int e = 0; e < expert; e++) offz += counts[e];

  const int tid = threadIdx.x;
  const int lane = tid & 63;
  const int wid = tid >> 6;
  const int wm = wid >> 1, wn = wid & 1;

  __shared__ unsigned short As[128 * 64];
  __shared__ unsigned short Bs[128 * 64];

  const int srow = tid >> 3;     // 0..31 within each 32-row issue
  const int schunk = tid & 7;    // 16B chunk within 128B row

  const unsigned short* aptr[4];
  const unsigned short* bptr[4];
  #pragma unroll
  for (int i = 0; i < 4; i++) {
    int rr = i * 32 + srow;
    int m = i_m * 128 + rr;
    int mm = (m < Ne) ? m : (Ne - 1);
    long arow;
    if (MODE == 0) arow = (long)tok_list[expert * T_TOK + mm] * KTOT;
    else           arow = (long)(offz + mm) * KTOT;
    // pre-swizzled global source (rule #21): LDS dest stays linear
    aptr[i] = Ag + arow + kbase + ((schunk ^ (rr & 7)) * 8);
    int nr = i_n * 128 + rr;
    bptr[i] = Bg + (long)expert * NB * KTOT + (long)nr * KTOT + kbase + ((schunk ^ (rr & 7)) * 8);
  }

  unsigned short* adst = As + wid * 512;
  unsigned short* bdst = Bs + wid * 512;

  f32x4 acc[4][4];
  #pragma unroll
  for (int i = 0; i < 4; i++)
    #pragma unroll
    for (int j = 0; j < 4; j++) acc[i][j] = (f32x4){0.f, 0.f, 0.f, 0.f};

  for (int k0 = 0; k0 < KTOT / KSPLIT; k0 += 64) {
    #pragma unroll
    for (int i = 0; i < 4; i++) {
      gll16(aptr[i] + k0, adst + i * 2048);
      gll16(bptr[i] + k0, bdst + i * 2048);
    }
    __syncthreads();   // compiler drains vmcnt before s_barrier
    #pragma unroll
    for (int kk = 0; kk < 2; kk++) {
      bf16x8 av[4], bv[4];
      #pragma unroll
      for (int i = 0; i < 4; i++) {
        int row = wm * 64 + i * 16 + (lane & 15);
        int ch = ((lane >> 4) + kk * 4) ^ (row & 7);
        av[i] = *(const bf16x8*)&As[row * 64 + ch * 8];
      }
      #pragma unroll
      for (int j = 0; j < 4; j++) {
        int row = wn * 64 + j * 16 + (lane & 15);
        int ch = ((lane >> 4) + kk * 4) ^ (row & 7);
        bv[j] = *(const bf16x8*)&Bs[row * 64 + ch * 8];
      }
      #pragma unroll
      for (int i = 0; i < 4; i++)
        #pragma unroll
        for (int j = 0; j < 4; j++)
          acc[i][j] = __builtin_amdgcn_mfma_f32_16x16x32_bf16(av[i], bv[j], acc[i][j], 0, 0, 0);
    }
    __syncthreads();
  }

  const int mbase = i_m * 128 + wm * 64 + (lane >> 4) * 4;
  const int nbase = i_n * 128 + wn * 64 + (lane & 15);
  #pragma unroll
  for (int i = 0; i < 4; i++) {
    #pragma unroll
    for (int j = 0; j < 4; j++) {
      #pragma unroll
      for (int rr = 0; rr < 4; rr++) {
        int m = mbase + i * 16 + rr;
        int n = nbase + j * 16;
        if (m < Ne) {
          float v = acc[i][j][rr];
          if (MODE == 0) {
            H[(long)(offz + m) * DFF + n] = f2bf(gelu_tanh(v));
          } else {
            float w = wt_list[expert * T_TOK + m];
            int token = tok_list[expert * T_TOK + m];
            atomicAdd(&out[(long)token * DIM + n], w * v);
          }
        }
      }
    }
  }
}

// ---------------- host ----------------
extern "C" void kernel_launch(void* const* d_in, const int* in_sizes, int n_in,
                              void* d_out, int out_size, void* d_ws, size_t ws_size,
                              hipStream_t stream) {
  const float* x    = (const float*)d_in[0];
  const float* wg1  = (const float*)d_in[1];
  const float* wg2  = (const float*)d_in[2];
  const float* ew1  = (const float*)d_in[3];
  const float* ew2  = (const float*)d_in[4];
  const float* cc   = (const float*)d_in[5];
  const float* cwg  = (const float*)d_in[6];

  float* out    = (float*)d_out;                      // [T,1024]
  float* logits = out + (size_t)T_TOK * DIM;          // [T,8]

  char* ws = (char*)d_ws;
  const size_t O_W1B  = 0;
  const size_t O_W2B  = O_W1B + (size_t)NREG * DFF * DIM * 2;
  const size_t O_X2B  = O_W2B + (size_t)NREG * DFF * DIM * 2;
  const size_t O_HTMP = O_X2B + (size_t)T_TOK * DIM * 2;
  const size_t O_CNT  = O_HTMP + (size_t)T_TOK * 64 * 4;
  const size_t O_WCC  = O_CNT + 256;
  const size_t O_TOK  = O_WCC + (size_t)T_TOK * 2 * 4;
  const size_t O_WT   = O_TOK + (size_t)NREG * T_TOK * 4;
  const size_t O_H    = O_WT + (size_t)NREG * T_TOK * 4;

  unsigned short* w1b  = (unsigned short*)(ws + O_W1B);
  unsigned short* w2b  = (unsigned short*)(ws + O_W2B);
  unsigned short* x2b  = (unsigned short*)(ws + O_X2B);
  float*          htmp = (float*)(ws + O_HTMP);
  int*            cnt  = (int*)(ws + O_CNT);
  float*          wcc  = (float*)(ws + O_WCC);
  int*            tok  = (int*)(ws + O_TOK);
  float*          wt   = (float*)(ws + O_WT);
  unsigned short* Hb   = (unsigned short*)(ws + O_H);

  convert_w_kernel<<<2048, 256, 0, stream>>>(ew1, ew2, w1b, w2b, cnt);
  router1_kernel<<<T_TOK / 64, 256, 0, stream>>>(x, wg1, htmp);
  gate_kernel<<<T_TOK / 256, 256, 0, stream>>>(htmp, wg2, logits, wcc, cnt, tok, wt);
  x2init_kernel<<<T_TOK, 256, 0, stream>>>(x, cc, cwg, wcc, x2b, out);
  gemm_kernel<DIM, DFF, 0, 1><<<dim3(DFF / 128, T_TOK / 128, NREG), 256, 0, stream>>>(
      x2b, w1b, Hb, nullptr, cnt, tok, wt);
  gemm_kernel<DFF, DIM, 1, 2><<<dim3(DIM / 128, T_TOK / 128, NREG * 2), 256, 0, stream>>>(
      Hb, w2b, nullptr, out, cnt, tok, wt);
}

// Round 6
// 508.134 us; speedup vs baseline: 1.2977x; 1.0313x over previous
//
#include <hip/hip_runtime.h>

#define T_TOK 8192
#define DIM   1024
#define DFF   4096
#define NEXP  8
#define NREG  5

typedef __attribute__((ext_vector_type(8))) __bf16 bf16x8;
typedef __attribute__((ext_vector_type(4))) float f32x4;
typedef __attribute__((ext_vector_type(4))) unsigned short us4;

__device__ inline unsigned short f2bf(float f) {
  unsigned int u = __builtin_bit_cast(unsigned int, f);
  u += 0x7fffu + ((u >> 16) & 1u);          // RNE
  return (unsigned short)(u >> 16);
}

__device__ inline void gll16(const void* g, void* l) {
  __builtin_amdgcn_global_load_lds(
      (__attribute__((address_space(1))) void*)(g),
      (__attribute__((address_space(3))) void*)(l), 16, 0, 0);
}

__device__ inline float gelu_tanh(float x) {
  float y = 0.7978845608028654f * (x + 0.044715f * x * x * x);
  float e = __expf(2.f * y);
  float t = 1.f - 2.f / (e + 1.f);
  return 0.5f * x * (1.f + t);
}

// ---------------- K1: weights fp32 -> bf16 (+ zero counts) ----------------
__global__ __launch_bounds__(256) void convert_w_kernel(
    const float* __restrict__ w1, const float* __restrict__ w2,
    unsigned short* __restrict__ w1b, unsigned short* __restrict__ w2b,
    int* __restrict__ counts) {
  if (blockIdx.x == 0 && threadIdx.x < 16) counts[threadIdx.x] = 0;
  const long N4 = (long)NREG * DFF * DIM / 4;   // float4 count per tensor
  long stride = (long)gridDim.x * 256;
  for (long p = (long)blockIdx.x * 256 + threadIdx.x; p < 2 * N4; p += stride) {
    const float* src = (p < N4) ? &w1[p * 4] : &w2[(p - N4) * 4];
    unsigned short* dst = (p < N4) ? &w1b[p * 4] : &w2b[(p - N4) * 4];
    float4 v = *(const float4*)src;
    us4 b = {f2bf(v.x), f2bf(v.y), f2bf(v.z), f2bf(v.w)};
    *(us4*)dst = b;
  }
}

// ---------------- K2: router layer 1: htmp = tanh(x @ wg1^T) ----------------
__global__ __launch_bounds__(256) void router1_kernel(
    const float* __restrict__ x, const float* __restrict__ wg1,
    float* __restrict__ htmp) {
  __shared__ float xs[64][68];
  __shared__ float ws[64][68];
  const int t0 = blockIdx.x * 64;
  const int tid = threadIdx.x;
  const int tr = tid >> 4, tc = tid & 15;
  float acc[4][4] = {};
  for (int k0 = 0; k0 < DIM; k0 += 64) {
    #pragma unroll
    for (int i = 0; i < 4; i++) {
      int idx = tid + i * 256;
      int r = idx >> 4, c4 = idx & 15;
      *(float4*)&xs[r][c4 * 4] = *(const float4*)&x[(long)(t0 + r) * DIM + k0 + c4 * 4];
      *(float4*)&ws[r][c4 * 4] = *(const float4*)&wg1[(long)r * DIM + k0 + c4 * 4];
    }
    __syncthreads();
    #pragma unroll
    for (int kk = 0; kk < 64; kk += 4) {
      float4 a[4], b[4];
      #pragma unroll
      for (int i = 0; i < 4; i++) a[i] = *(const float4*)&xs[tr * 4 + i][kk];
      #pragma unroll
      for (int j = 0; j < 4; j++) b[j] = *(const float4*)&ws[tc * 4 + j][kk];
      #pragma unroll
      for (int i = 0; i < 4; i++)
        #pragma unroll
        for (int j = 0; j < 4; j++)
          acc[i][j] += a[i].x * b[j].x + a[i].y * b[j].y + a[i].z * b[j].z + a[i].w * b[j].w;
    }
    __syncthreads();
  }
  #pragma unroll
  for (int i = 0; i < 4; i++)
    #pragma unroll
    for (int j = 0; j < 4; j++)
      htmp[(long)(t0 + tr * 4 + i) * 64 + tc * 4 + j] = tanhf(acc[i][j]);
}

// ---------------- K3: router layer 2 + gating + compaction ----------------
__global__ __launch_bounds__(256) void gate_kernel(
    const float* __restrict__ htmp, const float* __restrict__ wg2,
    float* __restrict__ logits_out, float* __restrict__ wcc,
    int* __restrict__ counts, int* __restrict__ tok_list,
    float* __restrict__ wt_list) {
  __shared__ float w2s[NEXP * 64];
  const int tid = threadIdx.x;
  for (int i = tid; i < NEXP * 64; i += 256) w2s[i] = wg2[i];
  __syncthreads();
  const int t = blockIdx.x * 256 + tid;

  float h[64];
  #pragma unroll
  for (int i = 0; i < 64; i += 4)
    *(float4*)&h[i] = *(const float4*)&htmp[(long)t * 64 + i];

  float lg[NEXP];
  #pragma unroll
  for (int e = 0; e < NEXP; e++) {
    float s = 0.f;
    #pragma unroll
    for (int j = 0; j < 64; j++) s += h[j] * w2s[e * 64 + j];
    lg[e] = s;
  }
  #pragma unroll
  for (int e = 0; e < NEXP; e++) logits_out[(long)t * NEXP + e] = lg[e];

  float m = lg[0];
  #pragma unroll
  for (int e = 1; e < NEXP; e++) m = fmaxf(m, lg[e]);
  float ex[NEXP], sum = 0.f;
  #pragma unroll
  for (int e = 0; e < NEXP; e++) { ex[e] = expf(lg[e] - m); sum += ex[e]; }

  int i1 = 0; float v1 = ex[0];
  #pragma unroll
  for (int e = 1; e < NEXP; e++) if (ex[e] > v1) { v1 = ex[e]; i1 = e; }
  int i2 = -1; float v2 = -1.f;
  #pragma unroll
  for (int e = 0; e < NEXP; e++) if (e != i1 && ex[e] > v2) { v2 = ex[e]; i2 = e; }
  v1 /= sum; v2 /= sum;
  float z1 = (i1 == NEXP - 1) ? 0.f : v1;
  float z2 = (i2 == NEXP - 1) ? 0.f : v2;
  float s2 = z1 + z2;
  float w1v = z1 / s2, w2v = z2 / s2;

  int   sel_i[2] = {i1, i2};
  float sel_w[2] = {w1v, w2v};
  float wc = 0.f, wcp = 0.f;
  #pragma unroll
  for (int s = 0; s < 2; s++) {
    int e = sel_i[s]; float w = sel_w[s];
    if (e < NREG) {
      int pos = atomicAdd(&counts[e], 1);
      tok_list[e * T_TOK + pos] = t;
      wt_list[e * T_TOK + pos] = w;
    } else if (e == NREG) wc = w;
    else if (e == NREG + 1) wcp = w;
  }
  wcc[t * 2 + 0] = wc;
  wcc[t * 2 + 1] = wcp;
}

// ---------------- K4: x2 = 2x -> bf16, out init with Const+Copy experts ----------------
__global__ __launch_bounds__(256) void x2init_kernel(
    const float* __restrict__ x, const float* __restrict__ const_c,
    const float* __restrict__ const_wg, const float* __restrict__ wcc,
    unsigned short* __restrict__ x2b, float* __restrict__ out) {
  const int t = blockIdx.x;
  const int tid = threadIdx.x;
  const int c0 = tid * 4;
  float4 v = *(const float4*)&x[(long)t * DIM + c0];
  float4 x2 = make_float4(2.f * v.x, 2.f * v.y, 2.f * v.z, 2.f * v.w);
  us4 xb = {f2bf(x2.x), f2bf(x2.y), f2bf(x2.z), f2bf(x2.w)};
  *(us4*)&x2b[(long)t * DIM + c0] = xb;

  float4 g0 = *(const float4*)&const_wg[c0];
  float4 g1 = *(const float4*)&const_wg[DIM + c0];
  float d0 = x2.x * g0.x + x2.y * g0.y + x2.z * g0.z + x2.w * g0.w;
  float d1 = x2.x * g1.x + x2.y * g1.y + x2.z * g1.z + x2.w * g1.w;
  #pragma unroll
  for (int off = 32; off; off >>= 1) {
    d0 += __shfl_down(d0, off);
    d1 += __shfl_down(d1, off);
  }
  __shared__ float red[8];
  const int lane = tid & 63, wid = tid >> 6;
  if (lane == 0) { red[wid] = d0; red[4 + wid] = d1; }
  __syncthreads();
  d0 = red[0] + red[1] + red[2] + red[3];
  d1 = red[4] + red[5] + red[6] + red[7];
  float mm = fmaxf(d0, d1);
  float e0 = expf(d0 - mm), e1 = expf(d1 - mm);
  float cw0 = e0 / (e0 + e1), cw1 = e1 / (e0 + e1);
  float wc = wcc[t * 2 + 0], wcp = wcc[t * 2 + 1];
  float4 cc = *(const float4*)&const_c[c0];
  float4 o;
  o.x = wc * (cw0 * x2.x + cw1 * cc.x) + wcp * x2.x;
  o.y = wc * (cw0 * x2.y + cw1 * cc.y) + wcp * x2.y;
  o.z = wc * (cw0 * x2.z + cw1 * cc.z) + wcp * x2.z;
  o.w = wc * (cw0 * x2.w + cw1 * cc.w) + wcp * x2.w;
  *(float4*)&out[(long)t * DIM + c0] = o;
}

// ---------------- K5/K6: bf16 MFMA GEMM, 128x128 tile, BK=128, 4 waves ----------------
// BK=128 single-buffer (64 KB LDS, 2 blocks/CU): halves the number of exposed
// full-latency drains per block (16->8) and doubles loads in flight per drain
// (16 gll16/thread) -> better miss concurrency, which the R1-R5 data identify
// as the binding constraint (dur ~= FETCH / 1.4-1.7 TB/s, MfmaUtil <= 17%).
// 2-D XCD rectangles kept from R5 (best FETCH). T5 setprio around MFMA cluster.
// MODE 0: C = gelu(Xg @ W1^T) -> H (bf16). A rows gathered via tok_list.
// MODE 1: out[token] += w * (H @ W2^T), split-K via z = expert*KSPLIT + ks.
template <int KTOT, int NB, int MODE, int KSPLIT>
__global__ __launch_bounds__(256) void gemm_kernel(
    const unsigned short* __restrict__ Ag, const unsigned short* __restrict__ Bg,
    unsigned short* __restrict__ H, float* __restrict__ out,
    const int* __restrict__ counts, const int* __restrict__ tok_list,
    const float* __restrict__ wt_list) {
  const int z = blockIdx.z;
  const int expert = MODE ? (z / KSPLIT) : z;
  const int kbase = MODE ? (z % KSPLIT) * (KTOT / KSPLIT) : 0;
  const int Ne = counts[expert];
  const int nact = (Ne + 127) >> 7;
  constexpr int NXB = NB / 128;               // N-panels in grid x
  const int p = blockIdx.y * NXB + blockIdx.x;
  if (p >= NXB * nact) return;

  // 2-D XCD rectangles: XC cols x XR rows of XCD-tiles over the (NXB x nact) grid
  constexpr int XC = (MODE == 0) ? 4 : 2;
  constexpr int XR = 8 / XC;
  constexpr int CW = NXB / XC;                // rect width in N-panels
  int i_n, i_m;
  if ((nact % XR) == 0) {
    const int xcd = p & 7, i = p >> 3;
    i_n = (xcd % XC) * CW + (i % CW);
    i_m = (xcd / XC) * (nact / XR) + (i / CW);
  } else {
    i_n = p % NXB;
    i_m = p / NXB;
  }
  if (i_m * 128 >= Ne) return;

  int offz = 0;
  for (int e = 0; e < expert; e++) offz += counts[e];

  const int tid = threadIdx.x;
  const int lane = tid & 63;
  const int wid = tid >> 6;
  const int wm = wid >> 1, wn = wid & 1;

  __shared__ unsigned short As[128 * 128];   // 32 KB
  __shared__ unsigned short Bs[128 * 128];   // 32 KB

  const int srow = tid >> 4;     // 0..15 within each 16-row issue
  const int schunk = tid & 15;   // 16B chunk within 256B row

  // 8 issues each for A and B; issue i covers rows i*16 .. i*16+15.
  // Pre-swizzled global source (rule #21); rr&7 == srow&7 for all i.
  const unsigned short* aptr[8];
  const unsigned short* bptr[8];
  const int swz = (schunk ^ (srow & 7)) * 8;
  #pragma unroll
  for (int i = 0; i < 8; i++) {
    int rr = i * 16 + srow;
    int m = i_m * 128 + rr;
    int mm = (m < Ne) ? m : (Ne - 1);
    long arow;
    if (MODE == 0) arow = (long)tok_list[expert * T_TOK + mm] * KTOT;
    else           arow = (long)(offz + mm) * KTOT;
    aptr[i] = Ag + arow + kbase + swz;
    int nr = i_n * 128 + rr;
    bptr[i] = Bg + (long)expert * NB * KTOT + (long)nr * KTOT + kbase + swz;
  }

  unsigned short* adst = As + wid * 512;   // + lane*8 elem implicit
  unsigned short* bdst = Bs + wid * 512;

  f32x4 acc[4][4];
  #pragma unroll
  for (int i = 0; i < 4; i++)
    #pragma unroll
    for (int j = 0; j < 4; j++) acc[i][j] = (f32x4){0.f, 0.f, 0.f, 0.f};

  for (int k0 = 0; k0 < KTOT / KSPLIT; k0 += 128) {
    #pragma unroll
    for (int i = 0; i < 8; i++) {
      gll16(aptr[i] + k0, adst + i * 2048);
      gll16(bptr[i] + k0, bdst + i * 2048);
    }
    __syncthreads();   // compiler drains vmcnt before s_barrier
    __builtin_amdgcn_s_setprio(1);
    #pragma unroll
    for (int kk = 0; kk < 4; kk++) {
      bf16x8 av[4], bv[4];
      #pragma unroll
      for (int i = 0; i < 4; i++) {
        int row = wm * 64 + i * 16 + (lane & 15);
        int ch = ((lane >> 4) + kk * 4) ^ (row & 7);
        av[i] = *(const bf16x8*)&As[row * 128 + ch * 8];
      }
      #pragma unroll
      for (int j = 0; j < 4; j++) {
        int row = wn * 64 + j * 16 + (lane & 15);
        int ch = ((lane >> 4) + kk * 4) ^ (row & 7);
        bv[j] = *(const bf16x8*)&Bs[row * 128 + ch * 8];
      }
      #pragma unroll
      for (int i = 0; i < 4; i++)
        #pragma unroll
        for (int j = 0; j < 4; j++)
          acc[i][j] = __builtin_amdgcn_mfma_f32_16x16x32_bf16(av[i], bv[j], acc[i][j], 0, 0, 0);
    }
    __builtin_amdgcn_s_setprio(0);
    __syncthreads();
  }

  const int mbase = i_m * 128 + wm * 64 + (lane >> 4) * 4;
  const int nbase = i_n * 128 + wn * 64 + (lane & 15);
  #pragma unroll
  for (int i = 0; i < 4; i++) {
    #pragma unroll
    for (int j = 0; j < 4; j++) {
      #pragma unroll
      for (int rr = 0; rr < 4; rr++) {
        int m = mbase + i * 16 + rr;
        int n = nbase + j * 16;
        if (m < Ne) {
          float v = acc[i][j][rr];
          if (MODE == 0) {
            H[(long)(offz + m) * DFF + n] = f2bf(gelu_tanh(v));
          } else {
            float w = wt_list[expert * T_TOK + m];
            int token = tok_list[expert * T_TOK + m];
            atomicAdd(&out[(long)token * DIM + n], w * v);
          }
        }
      }
    }
  }
}

// ---------------- host ----------------
extern "C" void kernel_launch(void* const* d_in, const int* in_sizes, int n_in,
                              void* d_out, int out_size, void* d_ws, size_t ws_size,
                              hipStream_t stream) {
  const float* x    = (const float*)d_in[0];
  const float* wg1  = (const float*)d_in[1];
  const float* wg2  = (const float*)d_in[2];
  const float* ew1  = (const float*)d_in[3];
  const float* ew2  = (const float*)d_in[4];
  const float* cc   = (const float*)d_in[5];
  const float* cwg  = (const float*)d_in[6];

  float* out    = (float*)d_out;                      // [T,1024]
  float* logits = out + (size_t)T_TOK * DIM;          // [T,8]

  char* ws = (char*)d_ws;
  const size_t O_W1B  = 0;
  const size_t O_W2B  = O_W1B + (size_t)NREG * DFF * DIM * 2;
  const size_t O_X2B  = O_W2B + (size_t)NREG * DFF * DIM * 2;
  const size_t O_HTMP = O_X2B + (size_t)T_TOK * DIM * 2;
  const size_t O_CNT  = O_HTMP + (size_t)T_TOK * 64 * 4;
  const size_t O_WCC  = O_CNT + 256;
  const size_t O_TOK  = O_WCC + (size_t)T_TOK * 2 * 4;
  const size_t O_WT   = O_TOK + (size_t)NREG * T_TOK * 4;
  const size_t O_H    = O_WT + (size_t)NREG * T_TOK * 4;

  unsigned short* w1b  = (unsigned short*)(ws + O_W1B);
  unsigned short* w2b  = (unsigned short*)(ws + O_W2B);
  unsigned short* x2b  = (unsigned short*)(ws + O_X2B);
  float*          htmp = (float*)(ws + O_HTMP);
  int*            cnt  = (int*)(ws + O_CNT);
  float*          wcc  = (float*)(ws + O_WCC);
  int*            tok  = (int*)(ws + O_TOK);
  float*          wt   = (float*)(ws + O_WT);
  unsigned short* Hb   = (unsigned short*)(ws + O_H);

  convert_w_kernel<<<2048, 256, 0, stream>>>(ew1, ew2, w1b, w2b, cnt);
  router1_kernel<<<T_TOK / 64, 256, 0, stream>>>(x, wg1, htmp);
  gate_kernel<<<T_TOK / 256, 256, 0, stream>>>(htmp, wg2, logits, wcc, cnt, tok, wt);
  x2init_kernel<<<T_TOK, 256, 0, stream>>>(x, cc, cwg, wcc, x2b, out);
  gemm_kernel<DIM, DFF, 0, 1><<<dim3(DFF / 128, T_TOK / 128, NREG), 256, 0, stream>>>(
      x2b, w1b, Hb, nullptr, cnt, tok, wt);
  gemm_kernel<DFF, DIM, 1, 2><<<dim3(DIM / 128, T_TOK / 128, NREG * 2), 256, 0, stream>>>(
      Hb, w2b, nullptr, out, cnt, tok, wt);
}

// Round 7
// 473.739 us; speedup vs baseline: 1.3919x; 1.0726x over previous
//
#include <hip/hip_runtime.h>

#define T_TOK 8192
#define DIM   1024
#define DFF   4096
#define NEXP  8
#define NREG  5
#define MAXMS 133   // worst-case sum over experts of ceil(Ne/128): 16384/128 + 5

typedef __attribute__((ext_vector_type(8))) __bf16 bf16x8;
typedef __attribute__((ext_vector_type(4))) float f32x4;
typedef __attribute__((ext_vector_type(4))) unsigned short us4;

__device__ inline unsigned short f2bf(float f) {
  unsigned int u = __builtin_bit_cast(unsigned int, f);
  u += 0x7fffu + ((u >> 16) & 1u);          // RNE
  return (unsigned short)(u >> 16);
}

__device__ inline void gll16(const void* g, void* l) {
  __builtin_amdgcn_global_load_lds(
      (__attribute__((address_space(1))) void*)(g),
      (__attribute__((address_space(3))) void*)(l), 16, 0, 0);
}

__device__ inline float gelu_tanh(float x) {
  float y = 0.7978845608028654f * (x + 0.044715f * x * x * x);
  float e = __expf(2.f * y);
  float t = 1.f - 2.f / (e + 1.f);
  return 0.5f * x * (1.f + t);
}

// ---------------- K1: weights fp32 -> bf16 (+ zero counts) ----------------
__global__ __launch_bounds__(256) void convert_w_kernel(
    const float* __restrict__ w1, const float* __restrict__ w2,
    unsigned short* __restrict__ w1b, unsigned short* __restrict__ w2b,
    int* __restrict__ counts) {
  if (blockIdx.x == 0 && threadIdx.x < 16) counts[threadIdx.x] = 0;
  const long N4 = (long)NREG * DFF * DIM / 4;   // float4 count per tensor
  long stride = (long)gridDim.x * 256;
  for (long p = (long)blockIdx.x * 256 + threadIdx.x; p < 2 * N4; p += stride) {
    const float* src = (p < N4) ? &w1[p * 4] : &w2[(p - N4) * 4];
    unsigned short* dst = (p < N4) ? &w1b[p * 4] : &w2b[(p - N4) * 4];
    float4 v = *(const float4*)src;
    us4 b = {f2bf(v.x), f2bf(v.y), f2bf(v.z), f2bf(v.w)};
    *(us4*)dst = b;
  }
}

// ---------------- K2: router layer 1: htmp = tanh(x @ wg1^T) ----------------
__global__ __launch_bounds__(256) void router1_kernel(
    const float* __restrict__ x, const float* __restrict__ wg1,
    float* __restrict__ htmp) {
  __shared__ float xs[64][68];
  __shared__ float ws[64][68];
  const int t0 = blockIdx.x * 64;
  const int tid = threadIdx.x;
  const int tr = tid >> 4, tc = tid & 15;
  float acc[4][4] = {};
  for (int k0 = 0; k0 < DIM; k0 += 64) {
    #pragma unroll
    for (int i = 0; i < 4; i++) {
      int idx = tid + i * 256;
      int r = idx >> 4, c4 = idx & 15;
      *(float4*)&xs[r][c4 * 4] = *(const float4*)&x[(long)(t0 + r) * DIM + k0 + c4 * 4];
      *(float4*)&ws[r][c4 * 4] = *(const float4*)&wg1[(long)r * DIM + k0 + c4 * 4];
    }
    __syncthreads();
    #pragma unroll
    for (int kk = 0; kk < 64; kk += 4) {
      float4 a[4], b[4];
      #pragma unroll
      for (int i = 0; i < 4; i++) a[i] = *(const float4*)&xs[tr * 4 + i][kk];
      #pragma unroll
      for (int j = 0; j < 4; j++) b[j] = *(const float4*)&ws[tc * 4 + j][kk];
      #pragma unroll
      for (int i = 0; i < 4; i++)
        #pragma unroll
        for (int j = 0; j < 4; j++)
          acc[i][j] += a[i].x * b[j].x + a[i].y * b[j].y + a[i].z * b[j].z + a[i].w * b[j].w;
    }
    __syncthreads();
  }
  #pragma unroll
  for (int i = 0; i < 4; i++)
    #pragma unroll
    for (int j = 0; j < 4; j++)
      htmp[(long)(t0 + tr * 4 + i) * 64 + tc * 4 + j] = tanhf(acc[i][j]);
}

// ---------------- K3: router layer 2 + gating + compaction ----------------
__global__ __launch_bounds__(256) void gate_kernel(
    const float* __restrict__ htmp, const float* __restrict__ wg2,
    float* __restrict__ logits_out, float* __restrict__ wcc,
    int* __restrict__ counts, int* __restrict__ tok_list,
    float* __restrict__ wt_list) {
  __shared__ float w2s[NEXP * 64];
  const int tid = threadIdx.x;
  for (int i = tid; i < NEXP * 64; i += 256) w2s[i] = wg2[i];
  __syncthreads();
  const int t = blockIdx.x * 256 + tid;

  float h[64];
  #pragma unroll
  for (int i = 0; i < 64; i += 4)
    *(float4*)&h[i] = *(const float4*)&htmp[(long)t * 64 + i];

  float lg[NEXP];
  #pragma unroll
  for (int e = 0; e < NEXP; e++) {
    float s = 0.f;
    #pragma unroll
    for (int j = 0; j < 64; j++) s += h[j] * w2s[e * 64 + j];
    lg[e] = s;
  }
  #pragma unroll
  for (int e = 0; e < NEXP; e++) logits_out[(long)t * NEXP + e] = lg[e];

  float m = lg[0];
  #pragma unroll
  for (int e = 1; e < NEXP; e++) m = fmaxf(m, lg[e]);
  float ex[NEXP], sum = 0.f;
  #pragma unroll
  for (int e = 0; e < NEXP; e++) { ex[e] = expf(lg[e] - m); sum += ex[e]; }

  int i1 = 0; float v1 = ex[0];
  #pragma unroll
  for (int e = 1; e < NEXP; e++) if (ex[e] > v1) { v1 = ex[e]; i1 = e; }
  int i2 = -1; float v2 = -1.f;
  #pragma unroll
  for (int e = 0; e < NEXP; e++) if (e != i1 && ex[e] > v2) { v2 = ex[e]; i2 = e; }
  v1 /= sum; v2 /= sum;
  float z1 = (i1 == NEXP - 1) ? 0.f : v1;
  float z2 = (i2 == NEXP - 1) ? 0.f : v2;
  float s2 = z1 + z2;
  float w1v = z1 / s2, w2v = z2 / s2;

  int   sel_i[2] = {i1, i2};
  float sel_w[2] = {w1v, w2v};
  float wc = 0.f, wcp = 0.f;
  #pragma unroll
  for (int s = 0; s < 2; s++) {
    int e = sel_i[s]; float w = sel_w[s];
    if (e < NREG) {
      int pos = atomicAdd(&counts[e], 1);
      tok_list[e * T_TOK + pos] = t;
      wt_list[e * T_TOK + pos] = w;
    } else if (e == NREG) wc = w;
    else if (e == NREG + 1) wcp = w;
  }
  wcc[t * 2 + 0] = wc;
  wcc[t * 2 + 1] = wcp;
}

// ---------------- K4: x2 = 2x -> bf16, out init with Const+Copy experts ----------------
__global__ __launch_bounds__(256) void x2init_kernel(
    const float* __restrict__ x, const float* __restrict__ const_c,
    const float* __restrict__ const_wg, const float* __restrict__ wcc,
    unsigned short* __restrict__ x2b, float* __restrict__ out) {
  const int t = blockIdx.x;
  const int tid = threadIdx.x;
  const int c0 = tid * 4;
  float4 v = *(const float4*)&x[(long)t * DIM + c0];
  float4 x2 = make_float4(2.f * v.x, 2.f * v.y, 2.f * v.z, 2.f * v.w);
  us4 xb = {f2bf(x2.x), f2bf(x2.y), f2bf(x2.z), f2bf(x2.w)};
  *(us4*)&x2b[(long)t * DIM + c0] = xb;

  float4 g0 = *(const float4*)&const_wg[c0];
  float4 g1 = *(const float4*)&const_wg[DIM + c0];
  float d0 = x2.x * g0.x + x2.y * g0.y + x2.z * g0.z + x2.w * g0.w;
  float d1 = x2.x * g1.x + x2.y * g1.y + x2.z * g1.z + x2.w * g1.w;
  #pragma unroll
  for (int off = 32; off; off >>= 1) {
    d0 += __shfl_down(d0, off);
    d1 += __shfl_down(d1, off);
  }
  __shared__ float red[8];
  const int lane = tid & 63, wid = tid >> 6;
  if (lane == 0) { red[wid] = d0; red[4 + wid] = d1; }
  __syncthreads();
  d0 = red[0] + red[1] + red[2] + red[3];
  d1 = red[4] + red[5] + red[6] + red[7];
  float mm = fmaxf(d0, d1);
  float e0 = expf(d0 - mm), e1 = expf(d1 - mm);
  float cw0 = e0 / (e0 + e1), cw1 = e1 / (e0 + e1);
  float wc = wcc[t * 2 + 0], wcp = wcc[t * 2 + 1];
  float4 cc = *(const float4*)&const_c[c0];
  float4 o;
  o.x = wc * (cw0 * x2.x + cw1 * cc.x) + wcp * x2.x;
  o.y = wc * (cw0 * x2.y + cw1 * cc.y) + wcp * x2.y;
  o.z = wc * (cw0 * x2.z + cw1 * cc.z) + wcp * x2.z;
  o.w = wc * (cw0 * x2.w + cw1 * cc.w) + wcp * x2.w;
  *(float4*)&out[(long)t * DIM + c0] = o;
}

// ---------------- K5/K6: bf16 MFMA GEMM, 128x128 tile, BK=64, 4 waves ----------------
// DENSE grid packing: grid.y enumerates only REAL (expert, M-block) slots via a
// counts prefix-walk (no empty-block clumps). R1-R6 data: the binding constraint
// is resident real blocks/CU (m97@4096 = 3 resident -> 590cy/K-step; our clumped
// grids ~1.3 resident -> 3000cy/K-step). Packing keeps every CU at its VGPR-limit
// residency (3 blocks) so stage drains overlap across blocks.
// MODE 0: C = gelu(Xg @ W1^T) -> H (bf16). A rows gathered via tok_list.
// MODE 1: out[token] += w * (H @ W2^T); split-K packed into grid.y (ks = y % KSPLIT).
template <int KTOT, int NB, int MODE, int KSPLIT>
__global__ __launch_bounds__(256) void gemm_kernel(
    const unsigned short* __restrict__ Ag, const unsigned short* __restrict__ Bg,
    unsigned short* __restrict__ H, float* __restrict__ out,
    const int* __restrict__ counts, const int* __restrict__ tok_list,
    const float* __restrict__ wt_list) {
  const int y = blockIdx.y;
  const int mslot = y / KSPLIT;
  const int ks = y % KSPLIT;
  const int kbase = ks * (KTOT / KSPLIT);

  // prefix-walk: mslot -> (expert, i_m, offz, Ne)
  int expert = -1, i_m = 0, offz = 0, Ne = 0;
  {
    int acc = 0, off = 0;
    #pragma unroll
    for (int e = 0; e < NREG; e++) {
      int ce = counts[e];
      int na = (ce + 127) >> 7;
      if (expert < 0 && mslot < acc + na) { expert = e; i_m = mslot - acc; offz = off; Ne = ce; }
      acc += na; off += ce;
    }
  }
  if (expert < 0) return;   // tail of the worst-case bound
  const int i_n = blockIdx.x;

  const int tid = threadIdx.x;
  const int lane = tid & 63;
  const int wid = tid >> 6;
  const int wm = wid >> 1, wn = wid & 1;

  __shared__ unsigned short As[128 * 64];
  __shared__ unsigned short Bs[128 * 64];

  const int srow = tid >> 3;     // 0..31 within each 32-row issue
  const int schunk = tid & 7;    // 16B chunk within 128B row

  const unsigned short* aptr[4];
  const unsigned short* bptr[4];
  #pragma unroll
  for (int i = 0; i < 4; i++) {
    int rr = i * 32 + srow;
    int m = i_m * 128 + rr;
    int mm = (m < Ne) ? m : (Ne - 1);
    long arow;
    if (MODE == 0) arow = (long)tok_list[expert * T_TOK + mm] * KTOT;
    else           arow = (long)(offz + mm) * KTOT;
    // pre-swizzled global source (rule #21): LDS dest stays linear
    aptr[i] = Ag + arow + kbase + ((schunk ^ (rr & 7)) * 8);
    int nr = i_n * 128 + rr;
    bptr[i] = Bg + (long)expert * NB * KTOT + (long)nr * KTOT + kbase + ((schunk ^ (rr & 7)) * 8);
  }

  unsigned short* adst = As + wid * 512;   // + lane*16B implicit
  unsigned short* bdst = Bs + wid * 512;

  f32x4 acc[4][4];
  #pragma unroll
  for (int i = 0; i < 4; i++)
    #pragma unroll
    for (int j = 0; j < 4; j++) acc[i][j] = (f32x4){0.f, 0.f, 0.f, 0.f};

  for (int k0 = 0; k0 < KTOT / KSPLIT; k0 += 64) {
    #pragma unroll
    for (int i = 0; i < 4; i++) {
      gll16(aptr[i] + k0, adst + i * 2048);
      gll16(bptr[i] + k0, bdst + i * 2048);
    }
    __syncthreads();   // compiler drains vmcnt before s_barrier
    __builtin_amdgcn_s_setprio(1);
    #pragma unroll
    for (int kk = 0; kk < 2; kk++) {
      bf16x8 av[4], bv[4];
      #pragma unroll
      for (int i = 0; i < 4; i++) {
        int row = wm * 64 + i * 16 + (lane & 15);
        int ch = ((lane >> 4) + kk * 4) ^ (row & 7);
        av[i] = *(const bf16x8*)&As[row * 64 + ch * 8];
      }
      #pragma unroll
      for (int j = 0; j < 4; j++) {
        int row = wn * 64 + j * 16 + (lane & 15);
        int ch = ((lane >> 4) + kk * 4) ^ (row & 7);
        bv[j] = *(const bf16x8*)&Bs[row * 64 + ch * 8];
      }
      #pragma unroll
      for (int i = 0; i < 4; i++)
        #pragma unroll
        for (int j = 0; j < 4; j++)
          acc[i][j] = __builtin_amdgcn_mfma_f32_16x16x32_bf16(av[i], bv[j], acc[i][j], 0, 0, 0);
    }
    __builtin_amdgcn_s_setprio(0);
    __syncthreads();
  }

  const int mbase = i_m * 128 + wm * 64 + (lane >> 4) * 4;
  const int nbase = i_n * 128 + wn * 64 + (lane & 15);
  #pragma unroll
  for (int i = 0; i < 4; i++) {
    #pragma unroll
    for (int j = 0; j < 4; j++) {
      #pragma unroll
      for (int rr = 0; rr < 4; rr++) {
        int m = mbase + i * 16 + rr;
        int n = nbase + j * 16;
        if (m < Ne) {
          float v = acc[i][j][rr];
          if (MODE == 0) {
            H[(long)(offz + m) * DFF + n] = f2bf(gelu_tanh(v));
          } else {
            float w = wt_list[expert * T_TOK + m];
            int token = tok_list[expert * T_TOK + m];
            atomicAdd(&out[(long)token * DIM + n], w * v);
          }
        }
      }
    }
  }
}

// ---------------- host ----------------
extern "C" void kernel_launch(void* const* d_in, const int* in_sizes, int n_in,
                              void* d_out, int out_size, void* d_ws, size_t ws_size,
                              hipStream_t stream) {
  const float* x    = (const float*)d_in[0];
  const float* wg1  = (const float*)d_in[1];
  const float* wg2  = (const float*)d_in[2];
  const float* ew1  = (const float*)d_in[3];
  const float* ew2  = (const float*)d_in[4];
  const float* cc   = (const float*)d_in[5];
  const float* cwg  = (const float*)d_in[6];

  float* out    = (float*)d_out;                      // [T,1024]
  float* logits = out + (size_t)T_TOK * DIM;          // [T,8]

  char* ws = (char*)d_ws;
  const size_t O_W1B  = 0;
  const size_t O_W2B  = O_W1B + (size_t)NREG * DFF * DIM * 2;
  const size_t O_X2B  = O_W2B + (size_t)NREG * DFF * DIM * 2;
  const size_t O_HTMP = O_X2B + (size_t)T_TOK * DIM * 2;
  const size_t O_CNT  = O_HTMP + (size_t)T_TOK * 64 * 4;
  const size_t O_WCC  = O_CNT + 256;
  const size_t O_TOK  = O_WCC + (size_t)T_TOK * 2 * 4;
  const size_t O_WT   = O_TOK + (size_t)NREG * T_TOK * 4;
  const size_t O_H    = O_WT + (size_t)NREG * T_TOK * 4;

  unsigned short* w1b  = (unsigned short*)(ws + O_W1B);
  unsigned short* w2b  = (unsigned short*)(ws + O_W2B);
  unsigned short* x2b  = (unsigned short*)(ws + O_X2B);
  float*          htmp = (float*)(ws + O_HTMP);
  int*            cnt  = (int*)(ws + O_CNT);
  float*          wcc  = (float*)(ws + O_WCC);
  int*            tok  = (int*)(ws + O_TOK);
  float*          wt   = (float*)(ws + O_WT);
  unsigned short* Hb   = (unsigned short*)(ws + O_H);

  convert_w_kernel<<<2048, 256, 0, stream>>>(ew1, ew2, w1b, w2b, cnt);
  router1_kernel<<<T_TOK / 64, 256, 0, stream>>>(x, wg1, htmp);
  gate_kernel<<<T_TOK / 256, 256, 0, stream>>>(htmp, wg2, logits, wcc, cnt, tok, wt);
  x2init_kernel<<<T_TOK, 256, 0, stream>>>(x, cc, cwg, wcc, x2b, out);
  // dense-packed grids: y enumerates real (expert, M-block[, ks]) slots only
  gemm_kernel<DIM, DFF, 0, 1><<<dim3(DFF / 128, MAXMS, 1), 256, 0, stream>>>(
      x2b, w1b, Hb, nullptr, cnt, tok, wt);
  gemm_kernel<DFF, DIM, 1, 2><<<dim3(DIM / 128, MAXMS * 2, 1), 256, 0, stream>>>(
      Hb, w2b, nullptr, out, cnt, tok, wt);
}